// Round 16
// baseline (23.428 us; speedup 1.0000x reference)
//
#include <hip/hip_runtime.h>
#include <math.h>

// RandISH, cooperative-tile v7: BARRIER-FREE wave-private quadrant transpose.
//   out[b, 2n+0] = Al(deg_n, r_b) * y0_norm[n] * P_l(ct)
//   out[b, 2n+1] = Al * cscale[n] * (-1)^deg * Re[(rx + i*ry)^deg]
// rv = vec[b] @ M[n]; rotation preserves |vec|=1 -> no normalization.
//
// Diagnosis of the 20.5us plateau (R11..R14): every s_barrier phase-locks
// the 32 resident waves/CU into {all-compute}/{all-store} lockstep (blocks
// launch together, phases equal length) -> the write pipe runs ~50% duty.
// The 6.5TB/s fill kernel has ZERO barriers.
//
// Fix: wave w computes bases n=8w..8w+7, i.e. dword columns 16w..16w+15 of
// EVERY row of the 64x64 tile -- and now also STORES exactly that column
// quadrant (4 chunks per row x 64 rows). Its ds_reads touch only its own
// ds_writes -> same-wave program order + lgkmcnt suffices: NO BARRIERS.
// Waves free-run and drift apart -> smooth store stream.
// Store inst = 16 runs of 64B (4 consecutive lanes) at 256B stride; 64B =
// HBM atom, so no partial-sector amplification (R4's 2.5x was 16B runs).
//
// lane (0..63) = direction b -> coalesced input loads; per-n data
// (readfirstlane-forced SGPR) -> scalar loads, uniform branches; Re[z^d]
// recurrence runs deg-1 real iterations (~54% run zero).
// LDS [64][65] (odd stride); block 256 thr, 2 tiles, grid 2048 = 8/CU.
//
// Re[z^d]: R_k = 2x R_{k-1} - (x^2+y^2) R_{k-2},  R_0=1, R_1=x.
// Al = exp2(-0.5*log2e*d(d+1)*(r+eps))  (0.5/(1/(r+e)+e) ~= 0.5(r+e), 1e-8).

#define NBASIS 32
#define PLEN 10
#define EPSV 1e-8f
#define LOG2E 1.44269504088896340736f
#define ROWD 65    // LDS row stride in dwords (odd -> conflict-free writes)
#define NT 2       // tiles per block

typedef float f32x4 __attribute__((ext_vector_type(4)));

__global__ __launch_bounds__(256) void randish_kernel(
    const float* __restrict__ vec,        // (B,3)
    const float* __restrict__ rough,      // (B,)
    const float* __restrict__ mats,       // (32,3,3)
    const float* __restrict__ coeffs,     // (32,10) increasing power
    const float* __restrict__ cscale,     // (32,)
    const float* __restrict__ y0n,        // (32,)
    const int*   __restrict__ degs,       // (32,)
    float* __restrict__ out,              // (B,64)
    int B)
{
    __shared__ float lds[64 * ROWD];      // 16.6 KB -> 8 blocks/CU (grid-capped)

    const int t    = threadIdx.x;         // 0..255
    const int lane = t & 63;              // direction within tile
    const int w    = __builtin_amdgcn_readfirstlane(t >> 6);  // wave id 0..3

    // ---- prefetch BOTH tiles' inputs (independent loads, one window) ----
    float V0[NT], V1[NT], V2[NT], TC[NT];
    int   BB[NT];
#pragma unroll
    for (int it = 0; it < NT; ++it) {
        const int b0 = (blockIdx.x * NT + it) * 64;
        const int b  = b0 + lane;         // B % (64*NT) == 0 -> in range
        BB[it] = b0;
        V0[it] = vec[b * 3 + 0];
        V1[it] = vec[b * 3 + 1];
        V2[it] = vec[b * 3 + 2];
        // Al = exp2( d*(d+1) * tc ),  tc = -0.5*log2e*(r+eps)
        TC[it] = (rough[b] + EPSV) * (-0.5f * LOG2E);
    }

    float* row = &lds[lane * ROWD];
    const int rl = lane >> 2;             // store-phase: row-local 0..15
    const int jl = lane & 3;              // store-phase: chunk-in-quadrant 0..3

#pragma unroll
    for (int it = 0; it < NT; ++it) {
        const float v0 = V0[it], v1 = V1[it], v2 = V2[it], tc = TC[it];

        // ---- compute 8 bases (this wave's column quadrant) into LDS ----
#pragma unroll
        for (int j = 0; j < 8; ++j) {
            const int n = 8 * w + j;      // SGPR-computed, wave-uniform
            const int d = __builtin_amdgcn_readfirstlane(degs[n]);
            const int par = d & 1;

            // rotate (|rv| == 1); mats entries are uniform scalar operands
            const float xh = fmaf(v0, mats[n*9+0], fmaf(v1, mats[n*9+3], v2 * mats[n*9+6]));
            const float yh = fmaf(v0, mats[n*9+1], fmaf(v1, mats[n*9+4], v2 * mats[n*9+7]));
            const float ct = fmaf(v0, mats[n*9+2], fmaf(v1, mats[n*9+5], v2 * mats[n*9+8]));

            // Legendre: P_l(ct) = ct^par * H(ct^2), parity-compressed
            const float ct2 = ct * ct;
            float v = coeffs[n*PLEN + par + 8];
            v = fmaf(v, ct2, coeffs[n*PLEN + par + 6]);
            v = fmaf(v, ct2, coeffs[n*PLEN + par + 4]);
            v = fmaf(v, ct2, coeffs[n*PLEN + par + 2]);
            v = fmaf(v, ct2, coeffs[n*PLEN + par + 0]);
            if (par) v *= ct;             // uniform branch

            // Re[(xh+i*yh)^d]: uniform trip count (d==1 -> zero iterations)
            float R = xh;
            if (d > 1) {
                const float ss  = fmaf(yh, yh, xh * xh);
                const float m2x = xh + xh;
                float Rm2 = 1.0f, Rm1 = xh;
                for (int k = 2; k <= d; ++k) {
                    const float Rk = fmaf(m2x, Rm1, -(ss * Rm2));
                    Rm2 = Rm1;
                    Rm1 = Rk;
                }
                R = Rm1;
            }
            float cs = cscale[n];
            if (par) cs = -cs;            // fold (-1)^deg, uniform

            const float al = __builtin_amdgcn_exp2f((float)(d * (d + 1)) * tc);

            // bank = (lane + 2n) % 32 -> <=2-way across 64 lanes (free)
            row[2 * n + 0] = al * (y0n[n] * v);
            row[2 * n + 1] = al * (cs * R);
        }

        // ---- NO BARRIER: this wave reads back only ITS OWN columns ----
        // (compiler orders same-address ds_write -> ds_read via lgkmcnt)

        // quadrant store: 64 rows x 4 chunks (cols 4w..4w+3), 4 insts;
        // each inst: 16 rows x 64B runs (4 consecutive lanes) @256B stride
        f32x4 o[4];
#pragma unroll
        for (int p = 0; p < 4; ++p) {
            const int r = p * 16 + rl;    // tile row
            const float* src = &lds[r * ROWD + (4 * w + jl) * 4];
            o[p] = f32x4{ src[0], src[1], src[2], src[3] };
        }
        f32x4* outp = reinterpret_cast<f32x4*>(out + (size_t)BB[it] * 64);
#pragma unroll
        for (int p = 0; p < 4; ++p) {
            const int c = (p * 16 + rl) * 16 + 4 * w + jl;  // chunk index
            __builtin_nontemporal_store(o[p], outp + c);
        }
        // next tile overwrites only this wave's own columns -> same-wave
        // WAR ordering via lgkmcnt (ds_read results already in VGPRs)
    }
}

extern "C" void kernel_launch(void* const* d_in, const int* in_sizes, int n_in,
                              void* d_out, int out_size, void* d_ws, size_t ws_size,
                              hipStream_t stream) {
    const float* vec    = (const float*)d_in[0];
    const float* rough  = (const float*)d_in[1];
    const float* mats   = (const float*)d_in[2];
    const float* coeffs = (const float*)d_in[3];
    const float* cscale = (const float*)d_in[4];
    const float* y0n    = (const float*)d_in[5];
    const int*   degs   = (const int*)d_in[6];
    float* out = (float*)d_out;

    const int B = in_sizes[1];            // roughness element count (262144)
    const int block = 256;                // 4 waves; 2 tiles of 64 directions
    const int grid = B / (64 * NT);       // 2048 blocks -> 8/CU, all resident

    randish_kernel<<<grid, block, 0, stream>>>(vec, rough, mats, coeffs, cscale,
                                               y0n, degs, out, B);
}

// Round 17
// 22.717 us; speedup vs baseline: 1.0313x; 1.0313x over previous
//
#include <hip/hip_runtime.h>
#include <math.h>

// RandISH v8: BARRIER-FREE wave-private HALF-TILE transpose, full-line NT runs.
//   out[b, 2n+0] = Al(deg_n, r_b) * y0_norm[n] * P_l(ct)
//   out[b, 2n+1] = Al * cscale[n] * (-1)^deg * Re[(rx + i*ry)^deg]
// rv = vec[b] @ M[n]; rotation preserves |vec|=1 -> no normalization.
//
// Evidence so far: store-run shape dominates (16B runs: 2.5x WRITE ampl.;
// 64B runs: -3us; 1KB runs: best 20.5us) and phase-locked barriers halve
// write duty (~3.3 TB/s effective). This kernel gets BOTH barrier-freedom
// and >=128B (full cache line) store runs:
//   wave = one 64-direction tile; lane = b. Compute bases 0..15 (left half
//   of every 256B output row) into a WAVE-PRIVATE 64x33 LDS buffer, then
//   8 ds_read_b128 + 8 NT stores; each store inst = 8 runs of 128B (full
//   line) at 256B stride. Repeat for bases 16..31 (right half).
// Cross-lane data moves through LDS within ONE wave -> in-order DS pipe
// guarantees write->read visibility: ZERO barriers; waves free-run.
//
// Block = 128 thr = 2 independent waves (wave k owns tile 2*bid+k);
// LDS = 2 x 64x33 dwords = 16.9 KB -> grid 2048 = 8 blocks/CU = 16 waves/CU.
//
// Per-n data wave-uniform (compile-time n -> literal scalar loads; uniform
// branches; Re[z^d] recurrence runs deg-1 real iterations, ~54% run zero).
// Re[z^d]: R_k = 2x R_{k-1} - (x^2+y^2) R_{k-2},  R_0=1, R_1=x.
// Al = exp2(-0.5*log2e*d(d+1)*(r+eps))  (0.5/(1/(r+e)+e) ~= 0.5(r+e), 1e-8).

#define NBASIS 32
#define PLEN 10
#define EPSV 1e-8f
#define LOG2E 1.44269504088896340736f
#define HROWD 33   // half-tile LDS row stride in dwords (odd -> conflict-free)

typedef float f32x4 __attribute__((ext_vector_type(4)));

__global__ __launch_bounds__(128) void randish_kernel(
    const float* __restrict__ vec,        // (B,3)
    const float* __restrict__ rough,      // (B,)
    const float* __restrict__ mats,       // (32,3,3)
    const float* __restrict__ coeffs,     // (32,10) increasing power
    const float* __restrict__ cscale,     // (32,)
    const float* __restrict__ y0n,        // (32,)
    const int*   __restrict__ degs,       // (32,)
    float* __restrict__ out,              // (B,64)
    int B)
{
    __shared__ float lds[2][64 * HROWD];  // per-wave private half-tile buffers

    const int t    = threadIdx.x;         // 0..127
    const int lane = t & 63;              // direction within tile
    const int k    = t >> 6;              // wave id 0/1 (owns its own tile)
    const int b0   = (blockIdx.x * 2 + k) * 64;
    const int b    = b0 + lane;           // B % 128 == 0 -> always in range

    const float v0 = vec[b * 3 + 0];
    const float v1 = vec[b * 3 + 1];
    const float v2 = vec[b * 3 + 2];
    // Al = exp2( d*(d+1) * tc ),  tc = -0.5*log2e*(r+eps)
    const float tc = (rough[b] + EPSV) * (-0.5f * LOG2E);

    float* row = &lds[k][lane * HROWD];
    const int rl = lane >> 3;             // store phase: row-in-group 0..7
    const int jl = lane & 7;              // store phase: chunk 0..7 in half-row
    f32x4* outp = reinterpret_cast<f32x4*>(out + (size_t)b0 * 64);

#pragma unroll
    for (int h = 0; h < 2; ++h) {         // half-tile: bases h*16 .. h*16+15
        // ---- compute 16 bases into this wave's private half-tile ----
#pragma unroll
        for (int j = 0; j < 16; ++j) {
            const int n = h * 16 + j;     // compile-time -> literal offsets
            const int d = __builtin_amdgcn_readfirstlane(degs[n]);
            const int par = d & 1;

            // rotate (|rv| == 1); mats entries are uniform scalar operands
            const float xh = fmaf(v0, mats[n*9+0], fmaf(v1, mats[n*9+3], v2 * mats[n*9+6]));
            const float yh = fmaf(v0, mats[n*9+1], fmaf(v1, mats[n*9+4], v2 * mats[n*9+7]));
            const float ct = fmaf(v0, mats[n*9+2], fmaf(v1, mats[n*9+5], v2 * mats[n*9+8]));

            // Legendre: P_l(ct) = ct^par * H(ct^2), parity-compressed
            const float ct2 = ct * ct;
            float v = coeffs[n*PLEN + par + 8];
            v = fmaf(v, ct2, coeffs[n*PLEN + par + 6]);
            v = fmaf(v, ct2, coeffs[n*PLEN + par + 4]);
            v = fmaf(v, ct2, coeffs[n*PLEN + par + 2]);
            v = fmaf(v, ct2, coeffs[n*PLEN + par + 0]);
            if (par) v *= ct;             // uniform branch

            // Re[(xh+i*yh)^d]: uniform trip count (d==1 -> zero iterations)
            float R = xh;
            if (d > 1) {
                const float ss  = fmaf(yh, yh, xh * xh);
                const float m2x = xh + xh;
                float Rm2 = 1.0f, Rm1 = xh;
                for (int q = 2; q <= d; ++q) {
                    const float Rq = fmaf(m2x, Rm1, -(ss * Rm2));
                    Rm2 = Rm1;
                    Rm1 = Rq;
                }
                R = Rm1;
            }
            float cs = cscale[n];
            if (par) cs = -cs;            // fold (-1)^deg, uniform

            const float al = __builtin_amdgcn_exp2f((float)(d * (d + 1)) * tc);

            // bank = (lane + 2j) % 32 -> 2 lanes/bank across 64 lanes (free)
            row[2 * j + 0] = al * (y0n[n] * v);
            row[2 * j + 1] = al * (cs * R);
        }

        // ---- NO BARRIER: same-wave DS pipe is in-order; cross-lane reads
        //      below see the writes above (wave-private buffer) ----
        f32x4 o[8];
#pragma unroll
        for (int p = 0; p < 8; ++p) {     // 512 chunks / 64 lanes
            const int r = p * 8 + rl;     // tile row
            const float* src = &lds[k][r * HROWD + jl * 4];
            o[p] = f32x4{ src[0], src[1], src[2], src[3] };
        }
#pragma unroll
        for (int p = 0; p < 8; ++p) {
            const int r = p * 8 + rl;
            // chunk = r*16 + h*8 + jl: 8 lanes -> 128B contiguous (full line)
            __builtin_nontemporal_store(o[p], outp + r * 16 + h * 8 + jl);
        }
        // h=1 overwrites row[] only after these ds_reads in program order
        // (same-wave WAR handled by in-order DS pipe + compiler waits)
    }
}

extern "C" void kernel_launch(void* const* d_in, const int* in_sizes, int n_in,
                              void* d_out, int out_size, void* d_ws, size_t ws_size,
                              hipStream_t stream) {
    const float* vec    = (const float*)d_in[0];
    const float* rough  = (const float*)d_in[1];
    const float* mats   = (const float*)d_in[2];
    const float* coeffs = (const float*)d_in[3];
    const float* cscale = (const float*)d_in[4];
    const float* y0n    = (const float*)d_in[5];
    const int*   degs   = (const int*)d_in[6];
    float* out = (float*)d_out;

    const int B = in_sizes[1];            // roughness element count (262144)
    const int block = 128;                // 2 independent waves, 1 tile each
    const int grid = B / 128;             // 2048 blocks -> 8/CU, all resident

    randish_kernel<<<grid, block, 0, stream>>>(vec, rough, mats, coeffs, cscale,
                                               y0n, degs, out, B);
}

// Round 18
// 20.633 us; speedup vs baseline: 1.1355x; 1.1010x over previous
//
#include <hip/hip_runtime.h>
#include <math.h>

// RandISH, DIAGNOSTIC build (R11 structure + DOUBLED NT stores).
//   out[b, 2n+0] = Al(deg_n, r_b) * y0_norm[n] * P_l(ct)
//   out[b, 2n+1] = Al * cscale[n] * (-1)^deg * Re[(rx + i*ry)^deg]
// rv = vec[b] @ M[n]; rotation preserves |vec|=1 -> no normalization.
//
// PURPOSE: 6 structural variants plateau at 20.5-23.4us vs ~13.5us ideal.
// This build issues every NT store TWICE (same addr+data: idempotent and
// validation-safe; NT bypasses L2 so HBM sees ~134MB of writes). The
// marginal cost of the 2nd 67MB separates the hypotheses:
//   drain-limited (~3.3TB/s effective): dur -> 38-41us  => R11 IS the
//     measured write ceiling for this stream shape; revert & declare.
//   issue/duty-limited (drain headroom): dur -> 22-26us => plateau is
//     recoverable via store-issue smearing; keep optimizing.
// Also: at ~40us the dispatch re-enters the top-5 rocprof rows, giving
// WRITE_SIZE/hbm_gbps for this structure for the first time.
//
// Structure = R11 (best, 20.5us): block 256 thr = 4 waves, 2 tiles, single
// LDS buffer [64][65], grid 2048 = 8 blocks/CU; lane=b, wave w -> bases
// 8w..8w+7 (wave-uniform SGPR constants); __syncthreads barriers; stores:
// consecutive threads -> consecutive 16B -> 1KB/wave full-line NT runs.
//
// Re[z^d]: R_k = 2x R_{k-1} - (x^2+y^2) R_{k-2},  R_0=1, R_1=x.
// Al = exp2(-0.5*log2e*d(d+1)*(r+eps))  (0.5/(1/(r+e)+e) ~= 0.5(r+e), 1e-8).

#define NBASIS 32
#define PLEN 10
#define EPSV 1e-8f
#define LOG2E 1.44269504088896340736f
#define ROWD 65    // LDS row stride in dwords (odd -> conflict-free)
#define NT 2       // tiles per block

typedef float f32x4 __attribute__((ext_vector_type(4)));

__global__ __launch_bounds__(256) void randish_kernel(
    const float* __restrict__ vec,        // (B,3)
    const float* __restrict__ rough,      // (B,)
    const float* __restrict__ mats,       // (32,3,3)
    const float* __restrict__ coeffs,     // (32,10) increasing power
    const float* __restrict__ cscale,     // (32,)
    const float* __restrict__ y0n,        // (32,)
    const int*   __restrict__ degs,       // (32,)
    float* __restrict__ out,              // (B,64)
    int B)
{
    __shared__ float lds[64 * ROWD];      // 16.6 KB -> 8 blocks/CU (grid-capped)

    const int t    = threadIdx.x;         // 0..255
    const int lane = t & 63;              // direction within tile
    const int w    = t >> 6;              // wave id 0..3

    // ---- prefetch BOTH tiles' inputs (independent loads, one window) ----
    float V0[NT], V1[NT], V2[NT], TC[NT];
    int   BB[NT];
#pragma unroll
    for (int it = 0; it < NT; ++it) {
        const int b0 = (blockIdx.x * NT + it) * 64;
        const int b  = b0 + lane;         // B % (64*NT) == 0 -> in range
        BB[it] = b0;
        V0[it] = vec[b * 3 + 0];
        V1[it] = vec[b * 3 + 1];
        V2[it] = vec[b * 3 + 2];
        // Al = exp2( d*(d+1) * tc ),  tc = -0.5*log2e*(r+eps)
        TC[it] = (rough[b] + EPSV) * (-0.5f * LOG2E);
    }

    float* row = &lds[lane * ROWD];

#pragma unroll
    for (int it = 0; it < NT; ++it) {
        const float v0 = V0[it], v1 = V1[it], v2 = V2[it], tc = TC[it];

        // ---- compute tile into LDS ----
#pragma unroll
        for (int j = 0; j < 8; ++j) {
            // n and all derived per-n data are wave-uniform -> SGPRs
            const int n = __builtin_amdgcn_readfirstlane(8 * w + j);
            const int d = __builtin_amdgcn_readfirstlane(degs[n]);
            const int par = d & 1;

            // rotate (|rv| == 1); mats entries are uniform scalar operands
            const float xh = fmaf(v0, mats[n*9+0], fmaf(v1, mats[n*9+3], v2 * mats[n*9+6]));
            const float yh = fmaf(v0, mats[n*9+1], fmaf(v1, mats[n*9+4], v2 * mats[n*9+7]));
            const float ct = fmaf(v0, mats[n*9+2], fmaf(v1, mats[n*9+5], v2 * mats[n*9+8]));

            // Legendre: P_l(ct) = ct^par * H(ct^2), parity-compressed
            const float ct2 = ct * ct;
            float v = coeffs[n*PLEN + par + 8];
            v = fmaf(v, ct2, coeffs[n*PLEN + par + 6]);
            v = fmaf(v, ct2, coeffs[n*PLEN + par + 4]);
            v = fmaf(v, ct2, coeffs[n*PLEN + par + 2]);
            v = fmaf(v, ct2, coeffs[n*PLEN + par + 0]);
            if (par) v *= ct;             // uniform branch

            // Re[(xh+i*yh)^d]: uniform trip count (d==1 -> zero iterations)
            float R = xh;
            if (d > 1) {
                const float ss  = fmaf(yh, yh, xh * xh);
                const float m2x = xh + xh;
                float Rm2 = 1.0f, Rm1 = xh;
                for (int k = 2; k <= d; ++k) {
                    const float Rk = fmaf(m2x, Rm1, -(ss * Rm2));
                    Rm2 = Rm1;
                    Rm1 = Rk;
                }
                R = Rm1;
            }
            float cs = cscale[n];
            if (par) cs = -cs;            // fold (-1)^deg, uniform

            const float al = __builtin_amdgcn_exp2f((float)(d * (d + 1)) * tc);

            // bank = (lane + 2n) % 32 -> <=2-way across 64 lanes (free)
            row[2 * n + 0] = al * (y0n[n] * v);
            row[2 * n + 1] = al * (cs * R);
        }

        __syncthreads();

        // ---- store tile TWICE (diagnostic): 2nd store reuses regs ----
        f32x4 o[4];
#pragma unroll
        for (int p = 0; p < 4; ++p) {
            const int c  = p * 256 + t;   // chunk index in tile
            const int r  = c >> 4;        // source LDS row
            const int c4 = (c & 15) * 4;  // dword column
            const float* src = &lds[r * ROWD + c4];
            o[p] = f32x4{ src[0], src[1], src[2], src[3] };
        }
        f32x4* outp = reinterpret_cast<f32x4*>(out + (size_t)BB[it] * 64);
#pragma unroll
        for (int p = 0; p < 4; ++p)
            __builtin_nontemporal_store(o[p], outp + p * 256 + t);
#pragma unroll
        for (int p = 0; p < 4; ++p)       // duplicate: pure marginal stores
            __builtin_nontemporal_store(o[p], outp + p * 256 + t);

        if (it + 1 < NT) __syncthreads(); // LDS reuse guard
    }
}

extern "C" void kernel_launch(void* const* d_in, const int* in_sizes, int n_in,
                              void* d_out, int out_size, void* d_ws, size_t ws_size,
                              hipStream_t stream) {
    const float* vec    = (const float*)d_in[0];
    const float* rough  = (const float*)d_in[1];
    const float* mats   = (const float*)d_in[2];
    const float* coeffs = (const float*)d_in[3];
    const float* cscale = (const float*)d_in[4];
    const float* y0n    = (const float*)d_in[5];
    const int*   degs   = (const int*)d_in[6];
    float* out = (float*)d_out;

    const int B = in_sizes[1];            // roughness element count (262144)
    const int block = 256;                // 4 waves; 2 tiles of 64 directions
    const int grid = B / (64 * NT);       // 2048 blocks -> 8/CU, all resident

    randish_kernel<<<grid, block, 0, stream>>>(vec, rough, mats, coeffs, cscale,
                                               y0n, degs, out, B);
}

// Round 19
// 20.367 us; speedup vs baseline: 1.1503x; 1.0131x over previous
//
#include <hip/hip_runtime.h>
#include <math.h>

// RandISH v9: R11 structure + degree-adaptive uniform fast paths.
//   out[b, 2n+0] = Al(deg_n, r_b) * y0_norm[n] * P_l(ct)
//   out[b, 2n+1] = Al * cscale[n] * (-1)^deg * Re[(rx + i*ry)^deg]
// rv = vec[b] @ M[n]; rotation preserves |vec|=1 -> no normalization.
//
// R17 diagnostic: doubling NT stores (134MB) cost ZERO -> not store-bound.
// Calibration vs R1 (70 wave-insts/128 outputs @ 40.7us, 65% VALUBusy) says
// the session tracks wave-inst count ~linearly: current ~35 insts -> 20.5us.
// So: cut VALU. deg is WAVE-UNIFORM -> scalar branches are cheap:
//  - deg==1 (~58% of bases): P1(ct)=ct exactly, Re[z]=xh -> skip Horner,
//    ct^2, parity-mul, recurrence: ~15 insts vs ~35.
//  - else: Horner runs exactly (d>>1)+1 terms via uniform branch tree with
//    compile-time coefficient offsets; recurrence runs d-1 iterations.
//
// Structure (R11, best): block 256 thr = 4 waves, 2 tiles/block, single
// LDS buffer [64][65] (odd stride, conflict-free), grid 2048 = 8 blocks/CU
// = 32 waves/CU all resident; lane=b (coalesced loads), wave w -> bases
// 8w..8w+7 (SGPR constants); NT full-line stores (consecutive threads ->
// consecutive 16B -> 1KB/wave runs).
//
// Re[z^d]: R_k = 2x R_{k-1} - (x^2+y^2) R_{k-2},  R_0=1, R_1=x.
// Al = exp2(-0.5*log2e*d(d+1)*(r+eps))  (0.5/(1/(r+e)+e) ~= 0.5(r+e), 1e-8).

#define NBASIS 32
#define PLEN 10
#define EPSV 1e-8f
#define LOG2E 1.44269504088896340736f
#define ROWD 65    // LDS row stride in dwords (odd -> conflict-free)
#define NT 2       // tiles per block

typedef float f32x4 __attribute__((ext_vector_type(4)));

__global__ __launch_bounds__(256) void randish_kernel(
    const float* __restrict__ vec,        // (B,3)
    const float* __restrict__ rough,      // (B,)
    const float* __restrict__ mats,       // (32,3,3)
    const float* __restrict__ coeffs,     // (32,10) increasing power
    const float* __restrict__ cscale,     // (32,)
    const float* __restrict__ y0n,        // (32,)
    const int*   __restrict__ degs,       // (32,)
    float* __restrict__ out,              // (B,64)
    int B)
{
    __shared__ float lds[64 * ROWD];      // 16.6 KB -> 8 blocks/CU (grid-capped)

    const int t    = threadIdx.x;         // 0..255
    const int lane = t & 63;              // direction within tile
    const int w    = t >> 6;              // wave id 0..3

    // ---- prefetch BOTH tiles' inputs (independent loads, one window) ----
    float V0[NT], V1[NT], V2[NT], TC[NT];
    int   BB[NT];
#pragma unroll
    for (int it = 0; it < NT; ++it) {
        const int b0 = (blockIdx.x * NT + it) * 64;
        const int b  = b0 + lane;         // B % (64*NT) == 0 -> in range
        BB[it] = b0;
        V0[it] = vec[b * 3 + 0];
        V1[it] = vec[b * 3 + 1];
        V2[it] = vec[b * 3 + 2];
        // Al = exp2( d*(d+1) * tc ),  tc = -0.5*log2e*(r+eps)
        TC[it] = (rough[b] + EPSV) * (-0.5f * LOG2E);
    }

    float* row = &lds[lane * ROWD];

#pragma unroll
    for (int it = 0; it < NT; ++it) {
        const float v0 = V0[it], v1 = V1[it], v2 = V2[it], tc = TC[it];

        // ---- compute tile into LDS ----
#pragma unroll
        for (int j = 0; j < 8; ++j) {
            // n and all derived per-n data are wave-uniform -> SGPRs
            const int n = __builtin_amdgcn_readfirstlane(8 * w + j);
            const int d = __builtin_amdgcn_readfirstlane(degs[n]);

            // rotate (|rv| == 1); mats entries are uniform scalar operands
            const float xh = fmaf(v0, mats[n*9+0], fmaf(v1, mats[n*9+3], v2 * mats[n*9+6]));
            const float yh = fmaf(v0, mats[n*9+1], fmaf(v1, mats[n*9+4], v2 * mats[n*9+7]));
            const float ct = fmaf(v0, mats[n*9+2], fmaf(v1, mats[n*9+5], v2 * mats[n*9+8]));

            const float al = __builtin_amdgcn_exp2f((float)(d * (d + 1)) * tc);

            float y0v, yl1v;
            if (d == 1) {
                // P1(ct) = ct exactly (c[1] == 1); Re[z^1] = xh; (-1)^1 fold
                y0v  = y0n[n] * ct;
                yl1v = -cscale[n] * xh;
            } else {
                const int par  = d & 1;
                const int base = n * PLEN + par;   // uniform runtime offset
                const float ct2 = ct * ct;

                // Horner with exactly (d>>1)+1 terms (uniform branch tree)
                const int K = d >> 1;              // 1..4 for d in [2,9]
                float v;
                if (K == 1) {
                    v = fmaf(coeffs[base+2], ct2, coeffs[base]);
                } else if (K == 2) {
                    v = fmaf(coeffs[base+4], ct2, coeffs[base+2]);
                    v = fmaf(v, ct2, coeffs[base]);
                } else if (K == 3) {
                    v = fmaf(coeffs[base+6], ct2, coeffs[base+4]);
                    v = fmaf(v, ct2, coeffs[base+2]);
                    v = fmaf(v, ct2, coeffs[base]);
                } else {
                    v = fmaf(coeffs[base+8], ct2, coeffs[base+6]);
                    v = fmaf(v, ct2, coeffs[base+4]);
                    v = fmaf(v, ct2, coeffs[base+2]);
                    v = fmaf(v, ct2, coeffs[base]);
                }
                if (par) v *= ct;                  // uniform branch

                // Re[(xh+i*yh)^d]: d-1 iterations (uniform trip count)
                const float ss  = fmaf(yh, yh, xh * xh);
                const float m2x = xh + xh;
                float Rm2 = 1.0f, Rm1 = xh;
                for (int k = 2; k <= d; ++k) {
                    const float Rk = fmaf(m2x, Rm1, -(ss * Rm2));
                    Rm2 = Rm1;
                    Rm1 = Rk;
                }
                float cs = cscale[n];
                if (par) cs = -cs;                 // fold (-1)^deg, uniform

                y0v  = y0n[n] * v;
                yl1v = cs * Rm1;
            }

            // bank = (lane + 2n) % 32 -> <=2-way across 64 lanes (free)
            row[2 * n + 0] = al * y0v;
            row[2 * n + 1] = al * yl1v;
        }

        __syncthreads();

        // ---- store tile: 1024 dwordx4 chunks, 4/thread; consecutive
        //      threads -> consecutive 16B -> 1KB/wave full-line NT runs ----
        f32x4 o[4];
#pragma unroll
        for (int p = 0; p < 4; ++p) {
            const int c  = p * 256 + t;   // chunk index in tile
            const int r  = c >> 4;        // source LDS row
            const int c4 = (c & 15) * 4;  // dword column
            const float* src = &lds[r * ROWD + c4];
            o[p] = f32x4{ src[0], src[1], src[2], src[3] };
        }
        f32x4* outp = reinterpret_cast<f32x4*>(out + (size_t)BB[it] * 64);
#pragma unroll
        for (int p = 0; p < 4; ++p)
            __builtin_nontemporal_store(o[p], outp + p * 256 + t);

        if (it + 1 < NT) __syncthreads(); // LDS reuse guard
    }
}

extern "C" void kernel_launch(void* const* d_in, const int* in_sizes, int n_in,
                              void* d_out, int out_size, void* d_ws, size_t ws_size,
                              hipStream_t stream) {
    const float* vec    = (const float*)d_in[0];
    const float* rough  = (const float*)d_in[1];
    const float* mats   = (const float*)d_in[2];
    const float* coeffs = (const float*)d_in[3];
    const float* cscale = (const float*)d_in[4];
    const float* y0n    = (const float*)d_in[5];
    const int*   degs   = (const int*)d_in[6];
    float* out = (float*)d_out;

    const int B = in_sizes[1];            // roughness element count (262144)
    const int block = 256;                // 4 waves; 2 tiles of 64 directions
    const int grid = B / (64 * NT);       // 2048 blocks -> 8/CU, all resident

    randish_kernel<<<grid, block, 0, stream>>>(vec, rough, mats, coeffs, cscale,
                                               y0n, degs, out, B);
}